// Round 12
// baseline (4926.548 us; speedup 1.0000x reference)
//
#include <hip/hip_runtime.h>
#include <hip/hip_bf16.h>
#include <hip/hip_cooperative_groups.h>

namespace cg = cooperative_groups;

// ---------------- problem dims ----------------
#define TT 40
#define BB 64
#define LL 80
#define DD 256
#define HH 1024
#define G4H 4096
#define AA 18
#define KENC 1280   // [demo(256) | h(1024)]
#define KLSTM 2048  // [x(1024) | h(1024)]
#define KCOMB 1280  // [attn(1024) | obs(256)]
#define NB 256
#define NT 512
#define QSZ (TT*BB*AA)

typedef __bf16 bf16x8 __attribute__((ext_vector_type(8)));
typedef float  f32x4  __attribute__((ext_vector_type(4)));

// ---------------- workspace layout (bytes) ----------------
#define OFF_WENC   ((size_t)0)
#define OFF_WLSTM  (OFF_WENC  + (size_t)G4H*KENC*2)
#define OFF_WCOMB  (OFF_WLSTM + (size_t)G4H*KLSTM*2)
#define OFF_WMID   (OFF_WCOMB + (size_t)HH*KCOMB*2)
#define OFF_BIASE  (OFF_WMID  + (size_t)HH*HH*2)
#define OFF_BIASL  (OFF_BIASE + (size_t)G4H*4)
#define OFF_DEMO   (OFF_BIASL + (size_t)G4H*4)
#define OFF_STATE  (OFF_DEMO  + (size_t)BB*LL*DD*2)
#define OFF_ENC    (OFF_STATE + (size_t)TT*BB*DD*2)
#define OFF_HDEC   (OFF_ENC   + (size_t)BB*LL*HH*2)
#define OFF_XALL   (OFF_HDEC  + (size_t)TT*BB*HH*2)
#define OFF_MF     (OFF_XALL  + (size_t)TT*BB*HH*2)
#define OFF_ATTNS  (OFF_MF    + (size_t)TT*BB*HH*2)
#define OFF_HROT   (OFF_ATTNS + (size_t)BB*HH*2)
#define NSLOT_E    81
#define NSLOT_D    41

// ---------------- helpers ----------------
__device__ __forceinline__ float sigm(float x){ return 1.f/(1.f+__expf(-x)); }

__device__ __forceinline__ float wred_sum(float v){
#pragma unroll
  for (int s=32; s>0; s>>=1) v += __shfl_xor(v, s, 64);
  return v;
}
__device__ __forceinline__ float wred_max(float v){
#pragma unroll
  for (int s=32; s>0; s>>=1) v = fmaxf(v, __shfl_xor(v, s, 64));
  return v;
}
__device__ __forceinline__ unsigned pack_bf16(float a, float b){
  unsigned short ua = __builtin_bit_cast(unsigned short, (__bf16)a);
  unsigned short ub = __builtin_bit_cast(unsigned short, (__bf16)b);
  return (unsigned)ua | ((unsigned)ub << 16);
}

// write-through (coherent) stores: visible at MALL, never stale in any L2.
// Kept so correctness does NOT depend on grid.sync()'s fence implementation.
__device__ __forceinline__ void st_u32_sc(unsigned* p, unsigned v){
  __hip_atomic_store(p, v, __ATOMIC_RELAXED, __HIP_MEMORY_SCOPE_AGENT);
}
__device__ __forceinline__ void st_b16_sc(__bf16* p, float v){
  unsigned short u = __builtin_bit_cast(unsigned short, (__bf16)v);
  asm volatile("global_store_short %0, %1, off sc0 sc1"
               :: "v"(p), "v"((unsigned)u) : "memory");
}

// ---------------- fused prologue (one dispatch) ----------------
// [0,4096) pack enc | [4096,8192) pack lstm | [8192,13312) comb
// [13312,17408) mid | [17408,22528) demo | [22528,25088) state
#define PB1 4096
#define PB2 8192
#define PB3 13312
#define PB4 17408
#define PB5 22528
#define PGRID 25088
__global__ __launch_bounds__(256)
void k_prep(const float* __restrict__ enc_wih, const float* __restrict__ enc_whh,
            const float* __restrict__ enc_bih, const float* __restrict__ enc_bhh,
            const float* __restrict__ lstm_wih, const float* __restrict__ lstm_whh,
            const float* __restrict__ lstm_bih, const float* __restrict__ lstm_bhh,
            const float* __restrict__ comb_w, const float* __restrict__ mid_w,
            const float* __restrict__ demo, const float* __restrict__ state,
            char* __restrict__ ws){
  int blk = blockIdx.x, tid = threadIdx.x;
  if (blk < PB1) {                    // pack enc gate rows
    int p = blk;
    int gate = p & 3, jj = (p >> 2) & 3, bq = p >> 4;
    int orig = gate*HH + bq*4 + jj;
    if (tid == 0) ((float*)(ws + OFF_BIASE))[p] = enc_bih[orig] + enc_bhh[orig];
    const float* s0 = enc_wih + (size_t)orig*DD;
    const float* s1 = enc_whh + (size_t)orig*HH;
    __bf16* d = (__bf16*)(ws + OFF_WENC) + (size_t)p*KENC;
    for (int k = tid; k < KENC; k += 256)
      d[k] = (__bf16)(k < DD ? s0[k] : s1[k-DD]);
  } else if (blk < PB2) {             // pack lstm gate rows
    int p = blk - PB1;
    int gate = p & 3, jj = (p >> 2) & 3, bq = p >> 4;
    int orig = gate*HH + bq*4 + jj;
    if (tid == 0) ((float*)(ws + OFF_BIASL))[p] = lstm_bih[orig] + lstm_bhh[orig];
    const float* s0 = lstm_wih + (size_t)orig*HH;
    const float* s1 = lstm_whh + (size_t)orig*HH;
    __bf16* d = (__bf16*)(ws + OFF_WLSTM) + (size_t)p*KLSTM;
    for (int k = tid; k < KLSTM; k += 256)
      d[k] = (__bf16)(k < HH ? s0[k] : s1[k-HH]);
  } else if (blk < PB3) {             // comb
    int i = (blk - PB2)*256 + tid;
    ((__bf16*)(ws + OFF_WCOMB))[i] = (__bf16)comb_w[i];
  } else if (blk < PB4) {             // mid
    int i = (blk - PB3)*256 + tid;
    ((__bf16*)(ws + OFF_WMID))[i] = (__bf16)mid_w[i];
  } else if (blk < PB5) {             // demo [B][L][D]
    int i = (blk - PB4)*256 + tid;
    ((__bf16*)(ws + OFF_DEMO))[i] = (__bf16)demo[i];
  } else {                            // state [T][B][D]
    int i = (blk - PB5)*256 + tid;
    ((__bf16*)(ws + OFF_STATE))[i] = (__bf16)state[i];
  }
}

// ---------------- persistent cooperative main kernel ----------------
// R7 structure (best persistent variant): 8 waves/block, waves 0-3 = K-half 0
// (m-tile wv&3), waves 4-7 = K-half 1. Partials meet in g_lds/g_lds2.
// Grid-wide sync = cooperative_groups grid.sync() (the one untried primitive).
__global__ __launch_bounds__(NT)
void k_main(const int* __restrict__ demlen,
            const float* __restrict__ h0, const float* __restrict__ c0,
            const float* __restrict__ attn_w,
            const float* __restrict__ comb_b, const float* __restrict__ mid_b,
            const float* __restrict__ out_w, const float* __restrict__ out_b,
            float* __restrict__ out, char* __restrict__ ws){
  cg::grid_group grid = cg::this_grid();
  const int bk = blockIdx.x, tid = threadIdx.x;
  const int wv = tid >> 6, ln = tid & 63;
  const int l15 = ln & 15, lhi = ln >> 4;
  const int klane = lhi * 8;
  const int gtid = bk*NT + tid;

  __bf16* wEnc  = (__bf16*)(ws + OFF_WENC);
  __bf16* wLstm = (__bf16*)(ws + OFF_WLSTM);
  __bf16* wComb = (__bf16*)(ws + OFF_WCOMB);
  __bf16* wMid  = (__bf16*)(ws + OFF_WMID);
  const float* bE = (const float*)(ws + OFF_BIASE);
  const float* bL = (const float*)(ws + OFF_BIASL);
  __bf16* demoC = (__bf16*)(ws + OFF_DEMO);
  __bf16* stateB= (__bf16*)(ws + OFF_STATE);
  __bf16* encB  = (__bf16*)(ws + OFF_ENC);
  __bf16* hdec  = (__bf16*)(ws + OFF_HDEC);
  __bf16* xall  = (__bf16*)(ws + OFF_XALL);
  __bf16* mf    = (__bf16*)(ws + OFF_MF);
  __bf16* attnS = (__bf16*)(ws + OFF_ATTNS);
  __bf16* hrotE = (__bf16*)(ws + OFF_HROT);
  __bf16* hrotD = hrotE + (size_t)NSLOT_E*BB*HH;

  __shared__ float g_lds [BB*17];   // K-half 0 partial gates (64x16, pad 17)
  __shared__ float g_lds2[BB*17];   // K-half 1 partial gates
  __shared__ float sc_sh[LL];
  __shared__ float w_sh[LL];

  const int m_ = tid >> 1, q2 = tid & 1;   // elementwise (tid<128): batch, col-pair
  const int j0_ = bk*4 + 2*q2;             // this thread's 2 h cols
  const int mt = wv & 3;                   // m-tile (16 batch rows)
  const int am = mt*16 + l15;              // this lane's A row (batch)
  const int khalf = wv >> 2;               // 0 or 1: K-half

  float cfa = 0.f, cfb = 0.f;              // cell state in registers

  // ---- init: zero enc h slot 0 ----
  for (int i = gtid; i < BB*HH/2; i += NB*NT) st_u32_sc((unsigned*)hrotE + i, 0u);
  grid.sync();

  // ================= encoder: 80 steps, K split 640/640 =================
  for (int t = 0; t < LL; ++t) {
    const __bf16* hR = hrotE + (size_t)t*BB*HH;
    const __bf16* brow = wEnc + (size_t)(bk*16 + l15)*KENC;
    const int kbase = khalf * 640;

    f32x4 acc = {0.f,0.f,0.f,0.f};
#pragma unroll 8
    for (int kk = 0; kk < 640; kk += 32) {
      int k0 = kbase + kk + klane;
      const __bf16* pa = (k0 < DD) ? demoC + ((size_t)am*LL + t)*DD + k0
                                   : hR + (size_t)am*HH + (k0 - DD);
      acc = __builtin_amdgcn_mfma_f32_16x16x32_bf16(*(const bf16x8*)pa,
                                                    *(const bf16x8*)(brow + k0), acc, 0,0,0);
    }
    {
      float* gl = khalf ? g_lds2 : g_lds;
      int r0 = mt*16 + lhi*4;
#pragma unroll
      for (int r = 0; r < 4; ++r) gl[(r0+r)*17 + l15] = acc[r];
    }
    __syncthreads();
    if (tid < 128) {
      char* hWg = (char*)(hrotE + (size_t)(t+1)*BB*HH);
      int gb = m_*17 + q2*8, cb = bk*16 + q2*8;
      float gi0 = g_lds[gb+0]+g_lds2[gb+0]+bE[cb+0], gf0 = g_lds[gb+1]+g_lds2[gb+1]+bE[cb+1];
      float gg0 = g_lds[gb+2]+g_lds2[gb+2]+bE[cb+2], go0 = g_lds[gb+3]+g_lds2[gb+3]+bE[cb+3];
      float gi1 = g_lds[gb+4]+g_lds2[gb+4]+bE[cb+4], gf1 = g_lds[gb+5]+g_lds2[gb+5]+bE[cb+5];
      float gg1 = g_lds[gb+6]+g_lds2[gb+6]+bE[cb+6], go1 = g_lds[gb+7]+g_lds2[gb+7]+bE[cb+7];
      float cn0 = sigm(gf0)*cfa + sigm(gi0)*tanhf(gg0);
      float cn1 = sigm(gf1)*cfb + sigm(gi1)*tanhf(gg1);
      float hn0 = sigm(go0)*tanhf(cn0);
      float hn1 = sigm(go1)*tanhf(cn1);
      cfa = cn0; cfb = cn1;
      unsigned hp = pack_bf16(hn0, hn1);
      st_u32_sc((unsigned*)(hWg + m_*2048 + j0_*2), hp);
      st_u32_sc((unsigned*)(encB + ((size_t)m_*LL + t)*HH + j0_), hp);
    }
    grid.sync();
  }

  // ================= phase S: static attention + decoder init ===============
  // softmax is h-independent: scores = score_d[b,l] + (h.Wh)[b] -> per-row
  // constant shift cancels. Attn weights shared across all decoder t.
  {
    int b = bk >> 2, qq = bk & 3;
    for (int i = 0; i < 10; ++i) {
      int l = wv*10 + i;
      const __bf16* er = encB + ((size_t)b*LL + l)*HH + ln*16;
      bf16x8 e0 = *(const bf16x8*)(er);
      bf16x8 e1 = *(const bf16x8*)(er + 8);
      float part = 0.f;
#pragma unroll
      for (int j = 0; j < 8; ++j) {
        part += (float)e0[j] * attn_w[ln*16 + j];
        part += (float)e1[j] * attn_w[ln*16 + 8 + j];
      }
      part = wred_sum(part);
      if (ln == 0) sc_sh[l] = part;
    }
    __syncthreads();
    if (wv == 0) {
      int len = demlen[b];
      float s0 = (ln < len) ? sc_sh[ln] : -1e30f;
      float s1 = (ln < 16 && 64+ln < len) ? sc_sh[64+ln] : -1e30f;
      float mx = wred_max(fmaxf(s0, s1));
      float e0 = __expf(s0 - mx);
      float e1 = (ln < 16) ? __expf(s1 - mx) : 0.f;
      float inv = 1.f / wred_sum(e0 + e1);
      w_sh[ln] = e0 * inv;
      if (ln < 16) w_sh[64+ln] = e1 * inv;
    }
    __syncthreads();
    if (tid < 256) {
      int col = qq*256 + tid;
      float a = 0.f;
      const __bf16* eb = encB + (size_t)b*LL*HH + col;
#pragma unroll 4
      for (int l = 0; l < LL; ++l) a += w_sh[l] * (float)eb[(size_t)l*HH];
      st_b16_sc(attnS + (size_t)b*HH + col, a);
    }
    for (int i = gtid; i < BB*HH/2; i += NB*NT) {
      int i2 = i*2;
      st_u32_sc((unsigned*)hrotD + i, pack_bf16(h0[i2], h0[i2+1]));
    }
    if (tid < 128) {
      cfa = c0[m_*HH + j0_];
      cfb = c0[m_*HH + j0_ + 1];
    }
  }
  grid.sync();

  // ================= phase X: x_all = relu([attn|obs_t]@combW^T + b) ========
  {
    int g = bk*8 + wv;
    for (int i = 0; i < 5; ++i) {
      int ti = i*2048 + g;             // 0..10239
      int mtt = ti >> 6, nt = ti & 63; // 160 m-tiles x 64 n-tiles
      f32x4 acc = {0.f,0.f,0.f,0.f};
      const __bf16* brow = wComb + (size_t)(nt*16 + l15)*KCOMB;
      int r = mtt*16 + l15, bb = r & 63;
      const __bf16* aat = attnS + (size_t)bb*HH;
      const __bf16* ast = stateB + (size_t)r*DD;
#pragma unroll 8
      for (int kk = 0; kk < KCOMB; kk += 32) {
        int k0 = kk + klane;
        bf16x8 af = (k0 < HH) ? *(const bf16x8*)(aat + k0)
                              : *(const bf16x8*)(ast + (k0-HH));
        acc = __builtin_amdgcn_mfma_f32_16x16x32_bf16(af, *(const bf16x8*)(brow + k0), acc, 0,0,0);
      }
      int col = nt*16 + l15;
      float cb = comb_b[col];
      int r0 = mtt*16 + lhi*4;
#pragma unroll
      for (int rr = 0; rr < 4; ++rr)
        st_b16_sc(xall + (size_t)(r0+rr)*HH + col, fmaxf(acc[rr]+cb, 0.f));
    }
  }
  grid.sync();

  // ================= decoder: 40 steps, K split 1024/1024 =================
  for (int t = 0; t < TT; ++t) {
    const __bf16* hR = hrotD + (size_t)t*BB*HH;
    const __bf16* brow = wLstm + (size_t)(bk*16 + l15)*KLSTM;
    const int kbase = khalf * HH;
    const __bf16* arow = khalf ? (hR + (size_t)am*HH)
                               : (xall + ((size_t)t*BB + am)*HH);

    f32x4 acc = {0.f,0.f,0.f,0.f};
#pragma unroll 8
    for (int kk = 0; kk < HH; kk += 32) {
      int k0 = kk + klane;
      acc = __builtin_amdgcn_mfma_f32_16x16x32_bf16(*(const bf16x8*)(arow + k0),
                                                    *(const bf16x8*)(brow + kbase + k0), acc, 0,0,0);
    }
    {
      float* gl = khalf ? g_lds2 : g_lds;
      int r0 = mt*16 + lhi*4;
#pragma unroll
      for (int r = 0; r < 4; ++r) gl[(r0+r)*17 + l15] = acc[r];
    }
    __syncthreads();
    if (tid < 128) {
      char* hWg = (char*)(hrotD + (size_t)(t+1)*BB*HH);
      int gb = m_*17 + q2*8, cb = bk*16 + q2*8;
      float gi0 = g_lds[gb+0]+g_lds2[gb+0]+bL[cb+0], gf0 = g_lds[gb+1]+g_lds2[gb+1]+bL[cb+1];
      float gg0 = g_lds[gb+2]+g_lds2[gb+2]+bL[cb+2], go0 = g_lds[gb+3]+g_lds2[gb+3]+bL[cb+3];
      float gi1 = g_lds[gb+4]+g_lds2[gb+4]+bL[cb+4], gf1 = g_lds[gb+5]+g_lds2[gb+5]+bL[cb+5];
      float gg1 = g_lds[gb+6]+g_lds2[gb+6]+bL[cb+6], go1 = g_lds[gb+7]+g_lds2[gb+7]+bL[cb+7];
      float cn0 = sigm(gf0)*cfa + sigm(gi0)*tanhf(gg0);
      float cn1 = sigm(gf1)*cfb + sigm(gi1)*tanhf(gg1);
      float hn0 = sigm(go0)*tanhf(cn0);
      float hn1 = sigm(go1)*tanhf(cn1);
      cfa = cn0; cfb = cn1;
      unsigned hp = pack_bf16(hn0, hn1);
      st_u32_sc((unsigned*)(hWg + m_*2048 + j0_*2), hp);
      st_u32_sc((unsigned*)(hdec + ((size_t)t*BB + m_)*HH + j0_), hp);
      if (t == TT-1) {   // exact fp32 final h from registers
        out[QSZ + m_*HH + j0_]     = hn0;
        out[QSZ + m_*HH + j0_ + 1] = hn1;
      }
    }
    grid.sync();
  }

  // final c (block-private cols, exact fp32 from registers)
  if (tid < 128) {
    out[QSZ + BB*HH + m_*HH + j0_]     = cfa;
    out[QSZ + BB*HH + m_*HH + j0_ + 1] = cfb;
  }

  // ================= epilogue: m = hdec @ midW^T + mid_b =================
  {
    int g = bk*8 + wv;
    for (int i = 0; i < 5; ++i) {
      int ti = i*2048 + g;
      int mtt = ti >> 6, nt = ti & 63;
      f32x4 acc = {0.f,0.f,0.f,0.f};
      const __bf16* brow = wMid + (size_t)(nt*16 + l15)*HH;
      const __bf16* arow2 = hdec + (size_t)(mtt*16 + l15)*HH;
#pragma unroll 8
      for (int kk = 0; kk < HH; kk += 32) {
        int k0 = kk + klane;
        acc = __builtin_amdgcn_mfma_f32_16x16x32_bf16(*(const bf16x8*)(arow2 + k0),
                                                      *(const bf16x8*)(brow + k0), acc, 0,0,0);
      }
      int col = nt*16 + l15;
      float mb = mid_b[col];
      int r0 = mtt*16 + lhi*4;
#pragma unroll
      for (int rr = 0; rr < 4; ++rr)
        st_b16_sc(mf + (size_t)(r0+rr)*HH + col, acc[rr]+mb);
    }
  }
  grid.sync();

  // ================= q = mf @ outW^T + out_b =================
  {
    int g = bk*8 + wv;
    for (int i = 0; i < 2; ++i) {
      int row = i*2048 + g;
      if (row < TT*BB) {
        const __bf16* mr = mf + (size_t)row*HH;
        float mreg[16];
#pragma unroll
        for (int k = 0; k < 16; ++k) mreg[k] = (float)mr[ln + 64*k];
        for (int a = 0; a < AA; ++a) {
          float p = 0.f;
#pragma unroll
          for (int k = 0; k < 16; ++k) p += mreg[k] * out_w[(size_t)a*HH + ln + 64*k];
          p = wred_sum(p);
          if (ln == 0) out[(size_t)row*AA + a] = p + out_b[a];
        }
      }
    }
  }
}

// ---------------- host launch ----------------
extern "C" void kernel_launch(void* const* d_in, const int* in_sizes, int n_in,
                              void* d_out, int out_size, void* d_ws, size_t ws_size,
                              hipStream_t stream) {
  (void)in_sizes; (void)n_in; (void)out_size; (void)ws_size;
  const float* state    = (const float*)d_in[0];
  const float* demo     = (const float*)d_in[1];
  const int*   demlen   = (const int*)d_in[2];
  const float* h0       = (const float*)d_in[3];
  const float* c0       = (const float*)d_in[4];
  const float* enc_wih  = (const float*)d_in[5];
  const float* enc_whh  = (const float*)d_in[6];
  const float* enc_bih  = (const float*)d_in[7];
  const float* enc_bhh  = (const float*)d_in[8];
  const float* attn_w   = (const float*)d_in[9];
  const float* comb_w   = (const float*)d_in[11];
  const float* comb_b   = (const float*)d_in[12];
  const float* lstm_wih = (const float*)d_in[13];
  const float* lstm_whh = (const float*)d_in[14];
  const float* lstm_bih = (const float*)d_in[15];
  const float* lstm_bhh = (const float*)d_in[16];
  const float* mid_w    = (const float*)d_in[17];
  const float* mid_b    = (const float*)d_in[18];
  const float* out_w    = (const float*)d_in[19];
  const float* out_b    = (const float*)d_in[20];
  char* ws = (char*)d_ws;
  float* outp = (float*)d_out;

  k_prep<<<PGRID, 256, 0, stream>>>(enc_wih, enc_whh, enc_bih, enc_bhh,
                                    lstm_wih, lstm_whh, lstm_bih, lstm_bhh,
                                    comb_w, mid_w, demo, state, ws);

  void* args[] = {
    (void*)&demlen, (void*)&h0, (void*)&c0, (void*)&attn_w,
    (void*)&comb_b, (void*)&mid_b, (void*)&out_w, (void*)&out_b,
    (void*)&outp, (void*)&ws
  };
  (void)hipLaunchCooperativeKernel(reinterpret_cast<void*>(k_main),
                                   dim3(NB), dim3(NT), args, 0, stream);
}

// Round 13
// 1911.497 us; speedup vs baseline: 2.5773x; 2.5773x over previous
//
#include <hip/hip_runtime.h>
#include <hip/hip_bf16.h>

// ---------------- problem dims ----------------
#define TT 40
#define BB 64
#define LL 80
#define DD 256
#define HH 1024
#define G4H 4096
#define AA 18
#define KENC 1280   // [demo(256) | h(1024)]
#define KLSTM 2048  // [x(1024) | h(1024)]
#define KCOMB 1280  // [attn(1024) | obs(256)]
#define QSZ (TT*BB*AA)

typedef __bf16 bf16x8 __attribute__((ext_vector_type(8)));
typedef float  f32x4  __attribute__((ext_vector_type(4)));

// ---------------- workspace layout (bytes) ----------------
#define OFF_WENC   ((size_t)0)
#define OFF_WLSTM  (OFF_WENC  + (size_t)G4H*KENC*2)
#define OFF_WCOMB  (OFF_WLSTM + (size_t)G4H*KLSTM*2)
#define OFF_WMID   (OFF_WCOMB + (size_t)HH*KCOMB*2)
#define OFF_BIASE  (OFF_WMID  + (size_t)HH*HH*2)
#define OFF_BIASL  (OFF_BIASE + (size_t)G4H*4)
#define OFF_DEMO   (OFF_BIASL + (size_t)G4H*4)
#define OFF_STATE  (OFF_DEMO  + (size_t)BB*LL*DD*2)
#define OFF_ENC    (OFF_STATE + (size_t)TT*BB*DD*2)
#define OFF_HDEC   (OFF_ENC   + (size_t)BB*LL*HH*2)
#define OFF_XALL   (OFF_HDEC  + (size_t)TT*BB*HH*2)
#define OFF_MF     (OFF_XALL  + (size_t)TT*BB*HH*2)
#define OFF_ATTNS  (OFF_MF    + (size_t)TT*BB*HH*2)
#define OFF_CF     (OFF_ATTNS + (size_t)BB*HH*2)
#define OFF_HBUF   (OFF_CF    + (size_t)BB*HH*4)   // 4 slots (encA,encB,decA,decB)

// ---------------- helpers ----------------
__device__ __forceinline__ float sigm(float x){ return 1.f/(1.f+__expf(-x)); }

__device__ __forceinline__ float wred_sum(float v){
#pragma unroll
  for (int s=32; s>0; s>>=1) v += __shfl_xor(v, s, 64);
  return v;
}
__device__ __forceinline__ float wred_max(float v){
#pragma unroll
  for (int s=32; s>0; s>>=1) v = fmaxf(v, __shfl_xor(v, s, 64));
  return v;
}
__device__ __forceinline__ unsigned pack_bf16(float a, float b){
  unsigned short ua = __builtin_bit_cast(unsigned short, (__bf16)a);
  unsigned short ub = __builtin_bit_cast(unsigned short, (__bf16)b);
  return (unsigned)ua | ((unsigned)ub << 16);
}

// ---------------- fused prologue (one dispatch) ----------------
// block ranges: [0,4096) pack enc | [4096,8192) pack lstm | [8192,13312) comb
// [13312,17408) mid | [17408,22528) demo | [22528,25088) state
// [25088,25344) zero cf | [25344,25472) zero hbE0
#define PB1 4096
#define PB2 8192
#define PB3 13312
#define PB4 17408
#define PB5 22528
#define PB6 25088
#define PB7 25344
#define PGRID 25472
__global__ __launch_bounds__(256)
void k_prep(const float* __restrict__ enc_wih, const float* __restrict__ enc_whh,
            const float* __restrict__ enc_bih, const float* __restrict__ enc_bhh,
            const float* __restrict__ lstm_wih, const float* __restrict__ lstm_whh,
            const float* __restrict__ lstm_bih, const float* __restrict__ lstm_bhh,
            const float* __restrict__ comb_w, const float* __restrict__ mid_w,
            const float* __restrict__ demo, const float* __restrict__ state,
            char* __restrict__ ws){
  int blk = blockIdx.x, tid = threadIdx.x;
  if (blk < PB1) {                    // pack enc gate rows
    int p = blk;
    int gate = p & 3, jj = (p >> 2) & 3, bq = p >> 4;
    int orig = gate*HH + bq*4 + jj;
    if (tid == 0) ((float*)(ws + OFF_BIASE))[p] = enc_bih[orig] + enc_bhh[orig];
    const float* s0 = enc_wih + (size_t)orig*DD;
    const float* s1 = enc_whh + (size_t)orig*HH;
    __bf16* d = (__bf16*)(ws + OFF_WENC) + (size_t)p*KENC;
    for (int k = tid; k < KENC; k += 256)
      d[k] = (__bf16)(k < DD ? s0[k] : s1[k-DD]);
  } else if (blk < PB2) {             // pack lstm gate rows
    int p = blk - PB1;
    int gate = p & 3, jj = (p >> 2) & 3, bq = p >> 4;
    int orig = gate*HH + bq*4 + jj;
    if (tid == 0) ((float*)(ws + OFF_BIASL))[p] = lstm_bih[orig] + lstm_bhh[orig];
    const float* s0 = lstm_wih + (size_t)orig*HH;
    const float* s1 = lstm_whh + (size_t)orig*HH;
    __bf16* d = (__bf16*)(ws + OFF_WLSTM) + (size_t)p*KLSTM;
    for (int k = tid; k < KLSTM; k += 256)
      d[k] = (__bf16)(k < HH ? s0[k] : s1[k-HH]);
  } else if (blk < PB3) {             // comb
    int i = (blk - PB2)*256 + tid;
    ((__bf16*)(ws + OFF_WCOMB))[i] = (__bf16)comb_w[i];
  } else if (blk < PB4) {             // mid
    int i = (blk - PB3)*256 + tid;
    ((__bf16*)(ws + OFF_WMID))[i] = (__bf16)mid_w[i];
  } else if (blk < PB5) {             // demo
    int i = (blk - PB4)*256 + tid;
    ((__bf16*)(ws + OFF_DEMO))[i] = (__bf16)demo[i];
  } else if (blk < PB6) {             // state
    int i = (blk - PB5)*256 + tid;
    ((__bf16*)(ws + OFF_STATE))[i] = (__bf16)state[i];
  } else if (blk < PB7) {             // zero cf
    int i = (blk - PB6)*256 + tid;
    ((float*)(ws + OFF_CF))[i] = 0.f;
  } else {                            // zero hbE0
    int i = (blk - PB7)*256 + tid;
    ((unsigned*)(ws + OFF_HBUF))[i] = 0u;
  }
}

// ---------------- encoder step: 256 blocks x 1024 thr (16 waves) ----------
// wave = (mt = wv&3, kq = wv>>2): m-tile mt, K-chunk kq*320..+320 of K=1280.
__global__ __launch_bounds__(1024)
void k_enc_step(const __bf16* __restrict__ demoC, const __bf16* __restrict__ wEnc,
                const float* __restrict__ bE, const __bf16* __restrict__ hR,
                __bf16* __restrict__ hW, __bf16* __restrict__ encB,
                float* __restrict__ cf, int t){
  const int bk = blockIdx.x, tid = threadIdx.x;
  const int wv = tid >> 6, ln = tid & 63;
  const int l15 = ln & 15, lhi = ln >> 4;
  const int klane = lhi * 8;
  const int mt = wv & 3, kq = wv >> 2;
  const int am = mt*16 + l15;

  __shared__ float g_lds[4][BB*17];

  const __bf16* brow = wEnc + (size_t)(bk*16 + l15)*KENC;
  const __bf16* arow = demoC + ((size_t)am*LL + t)*DD;
  const __bf16* hrow = hR + (size_t)am*HH;

  f32x4 acc = {0.f,0.f,0.f,0.f};
  const int kb = kq*320;
#pragma unroll
  for (int kk = 0; kk < 320; kk += 32) {
    int k0 = kb + kk + klane;
    const __bf16* pa = (k0 < DD) ? (arow + k0) : (hrow + (k0 - DD));
    acc = __builtin_amdgcn_mfma_f32_16x16x32_bf16(*(const bf16x8*)pa,
                                                  *(const bf16x8*)(brow + k0), acc, 0,0,0);
  }
  {
    int r0 = mt*16 + lhi*4;
#pragma unroll
    for (int r = 0; r < 4; ++r) g_lds[kq][(r0+r)*17 + l15] = acc[r];
  }
  __syncthreads();
  if (tid < 128) {
    const int m_ = tid >> 1, q2 = tid & 1;
    const int j0_ = bk*4 + 2*q2;
    int gb = m_*17 + q2*8, cb = bk*16 + q2*8;
    float g[8];
#pragma unroll
    for (int j = 0; j < 8; ++j)
      g[j] = g_lds[0][gb+j] + g_lds[1][gb+j] + g_lds[2][gb+j] + g_lds[3][gb+j] + bE[cb+j];
    float cA = cf[m_*HH + j0_], cB = cf[m_*HH + j0_ + 1];
    float cn0 = sigm(g[1])*cA + sigm(g[0])*tanhf(g[2]);
    float cn1 = sigm(g[5])*cB + sigm(g[4])*tanhf(g[6]);
    float hn0 = sigm(g[3])*tanhf(cn0);
    float hn1 = sigm(g[7])*tanhf(cn1);
    cf[m_*HH + j0_] = cn0; cf[m_*HH + j0_ + 1] = cn1;
    unsigned hp = pack_bf16(hn0, hn1);
    *(unsigned*)(hW + (size_t)m_*HH + j0_) = hp;
    *(unsigned*)(encB + ((size_t)m_*LL + t)*HH + j0_) = hp;
  }
}

// ---------------- decoder step: 256 blocks x 1024 thr (16 waves) ----------
// wave = (mt, kq): K-chunk kq*512..+512 of K=2048 (chunks 0-1 = x, 2-3 = h).
__global__ __launch_bounds__(1024)
void k_dec_step(const __bf16* __restrict__ xall, const __bf16* __restrict__ wLstm,
                const float* __restrict__ bL, const __bf16* __restrict__ hR,
                __bf16* __restrict__ hW, __bf16* __restrict__ hdec,
                float* __restrict__ cf, float* __restrict__ out, int t){
  const int bk = blockIdx.x, tid = threadIdx.x;
  const int wv = tid >> 6, ln = tid & 63;
  const int l15 = ln & 15, lhi = ln >> 4;
  const int klane = lhi * 8;
  const int mt = wv & 3, kq = wv >> 2;
  const int am = mt*16 + l15;

  __shared__ float g_lds[4][BB*17];

  const __bf16* brow = wLstm + (size_t)(bk*16 + l15)*KLSTM + kq*512;
  const __bf16* arow = (kq < 2) ? (xall + ((size_t)t*BB + am)*HH + kq*512)
                                : (hR + (size_t)am*HH + (kq-2)*512);

  f32x4 acc = {0.f,0.f,0.f,0.f};
#pragma unroll
  for (int kk = 0; kk < 512; kk += 32) {
    int k0 = kk + klane;
    acc = __builtin_amdgcn_mfma_f32_16x16x32_bf16(*(const bf16x8*)(arow + k0),
                                                  *(const bf16x8*)(brow + k0), acc, 0,0,0);
  }
  {
    int r0 = mt*16 + lhi*4;
#pragma unroll
    for (int r = 0; r < 4; ++r) g_lds[kq][(r0+r)*17 + l15] = acc[r];
  }
  __syncthreads();
  if (tid < 128) {
    const int m_ = tid >> 1, q2 = tid & 1;
    const int j0_ = bk*4 + 2*q2;
    int gb = m_*17 + q2*8, cb = bk*16 + q2*8;
    float g[8];
#pragma unroll
    for (int j = 0; j < 8; ++j)
      g[j] = g_lds[0][gb+j] + g_lds[1][gb+j] + g_lds[2][gb+j] + g_lds[3][gb+j] + bL[cb+j];
    float cA = cf[m_*HH + j0_], cB = cf[m_*HH + j0_ + 1];
    float cn0 = sigm(g[1])*cA + sigm(g[0])*tanhf(g[2]);
    float cn1 = sigm(g[5])*cB + sigm(g[4])*tanhf(g[6]);
    float hn0 = sigm(g[3])*tanhf(cn0);
    float hn1 = sigm(g[7])*tanhf(cn1);
    cf[m_*HH + j0_] = cn0; cf[m_*HH + j0_ + 1] = cn1;
    unsigned hp = pack_bf16(hn0, hn1);
    *(unsigned*)(hW + (size_t)m_*HH + j0_) = hp;
    *(unsigned*)(hdec + ((size_t)t*BB + m_)*HH + j0_) = hp;
    if (t == TT-1) {   // exact fp32 final h straight from registers
      out[QSZ + m_*HH + j0_]     = hn0;
      out[QSZ + m_*HH + j0_ + 1] = hn1;
    }
  }
}

// ---------------- static attention + decoder state init ----------------
// softmax is h-independent: scores = score_d[b,l] + (h.Wh)[b] -> per-row
// constant shift cancels. Attn weights shared across all decoder t.
__global__ __launch_bounds__(256)
void k_attn(const int* __restrict__ demlen, const float* __restrict__ h0,
            const float* __restrict__ c0, const float* __restrict__ attn_w,
            const __bf16* __restrict__ encB, __bf16* __restrict__ attnS,
            __bf16* __restrict__ hD0, float* __restrict__ cf){
  const int bk = blockIdx.x, tid = threadIdx.x;
  const int wv = tid >> 6, ln = tid & 63;
  __shared__ float sc_sh[LL];
  __shared__ float w_sh[LL];
  int b = bk >> 2, qq = bk & 3;
  for (int i = 0; i < 20; ++i) {
    int l = wv*20 + i;
    const __bf16* er = encB + ((size_t)b*LL + l)*HH + ln*16;
    bf16x8 e0 = *(const bf16x8*)(er);
    bf16x8 e1 = *(const bf16x8*)(er + 8);
    float part = 0.f;
#pragma unroll
    for (int j = 0; j < 8; ++j) {
      part += (float)e0[j] * attn_w[ln*16 + j];
      part += (float)e1[j] * attn_w[ln*16 + 8 + j];
    }
    part = wred_sum(part);
    if (ln == 0) sc_sh[l] = part;
  }
  __syncthreads();
  if (wv == 0) {
    int len = demlen[b];
    float s0 = (ln < len) ? sc_sh[ln] : -1e30f;
    float s1 = (ln < 16 && 64+ln < len) ? sc_sh[64+ln] : -1e30f;
    float mx = wred_max(fmaxf(s0, s1));
    float e0 = __expf(s0 - mx);
    float e1 = (ln < 16) ? __expf(s1 - mx) : 0.f;
    float inv = 1.f / wred_sum(e0 + e1);
    w_sh[ln] = e0 * inv;
    if (ln < 16) w_sh[64+ln] = e1 * inv;
  }
  __syncthreads();
  {
    int col = qq*256 + tid;
    float a = 0.f;
    const __bf16* eb = encB + (size_t)b*LL*HH + col;
#pragma unroll 4
    for (int l = 0; l < LL; ++l) a += w_sh[l] * (float)eb[(size_t)l*HH];
    attnS[(size_t)b*HH + col] = (__bf16)a;
  }
  // decoder state init (grid-stride)
  int gtid = bk*256 + tid;
  for (int i = gtid; i < BB*HH/2; i += 256*256) {
    int i2 = i*2;
    *((unsigned*)hD0 + i) = pack_bf16(h0[i2], h0[i2+1]);
  }
  for (int i = gtid; i < BB*HH; i += 256*256) cf[i] = c0[i];
}

// ---------------- phase X: x_all = relu([attn|obs_t] @ combW^T + b) --------
__global__ __launch_bounds__(256)
void k_x(const __bf16* __restrict__ attnS, const __bf16* __restrict__ stateB,
         const __bf16* __restrict__ wComb, const float* __restrict__ comb_b,
         __bf16* __restrict__ xall){
  const int bk = blockIdx.x, tid = threadIdx.x;
  const int wv = tid >> 6, ln = tid & 63;
  const int l15 = ln & 15, lhi = ln >> 4;
  const int klane = lhi * 8;
  int g = bk*4 + wv;
  for (int i = 0; i < 10; ++i) {
    int ti = i*1024 + g;            // 0..10239
    int mtt = ti >> 6, nt = ti & 63;
    f32x4 acc = {0.f,0.f,0.f,0.f};
    const __bf16* brow = wComb + (size_t)(nt*16 + l15)*KCOMB;
    int r = mtt*16 + l15, bb = r & 63;
    const __bf16* aat = attnS + (size_t)bb*HH;
    const __bf16* ast = stateB + (size_t)r*DD;
#pragma unroll 8
    for (int kk = 0; kk < KCOMB; kk += 32) {
      int k0 = kk + klane;
      bf16x8 af = (k0 < HH) ? *(const bf16x8*)(aat + k0)
                            : *(const bf16x8*)(ast + (k0-HH));
      acc = __builtin_amdgcn_mfma_f32_16x16x32_bf16(af, *(const bf16x8*)(brow + k0), acc, 0,0,0);
    }
    int col = nt*16 + l15;
    float cb = comb_b[col];
    int r0 = mtt*16 + lhi*4;
#pragma unroll
    for (int rr = 0; rr < 4; ++rr)
      xall[(size_t)(r0+rr)*HH + col] = (__bf16)fmaxf(acc[rr]+cb, 0.f);
  }
}

// ---------------- epilogue: m = hdec @ midW^T + mid_b ----------------
__global__ __launch_bounds__(256)
void k_mid(const __bf16* __restrict__ hdec, const __bf16* __restrict__ wMid,
           const float* __restrict__ mid_b, __bf16* __restrict__ mf){
  const int bk = blockIdx.x, tid = threadIdx.x;
  const int wv = tid >> 6, ln = tid & 63;
  const int l15 = ln & 15, lhi = ln >> 4;
  const int klane = lhi * 8;
  int g = bk*4 + wv;
  for (int i = 0; i < 10; ++i) {
    int ti = i*1024 + g;
    int mtt = ti >> 6, nt = ti & 63;
    f32x4 acc = {0.f,0.f,0.f,0.f};
    const __bf16* brow = wMid + (size_t)(nt*16 + l15)*HH;
    const __bf16* arow = hdec + (size_t)(mtt*16 + l15)*HH;
#pragma unroll 8
    for (int kk = 0; kk < HH; kk += 32) {
      int k0 = kk + klane;
      acc = __builtin_amdgcn_mfma_f32_16x16x32_bf16(*(const bf16x8*)(arow + k0),
                                                    *(const bf16x8*)(brow + k0), acc, 0,0,0);
    }
    int col = nt*16 + l15;
    float mb = mid_b[col];
    int r0 = mtt*16 + lhi*4;
#pragma unroll
    for (int rr = 0; rr < 4; ++rr)
      mf[(size_t)(r0+rr)*HH + col] = (__bf16)(acc[rr]+mb);
  }
}

// ---------------- q = mf @ outW^T + out_b ; final c copy ----------------
__global__ __launch_bounds__(256)
void k_out(const __bf16* __restrict__ mf, const float* __restrict__ out_w,
           const float* __restrict__ out_b, const float* __restrict__ cf,
           float* __restrict__ out){
  const int bk = blockIdx.x, tid = threadIdx.x;
  const int wv = tid >> 6, ln = tid & 63;
  int g = bk*4 + wv;
  for (int i = 0; i < 3; ++i) {
    int row = i*1024 + g;
    if (row < TT*BB) {
      const __bf16* mr = mf + (size_t)row*HH;
      float mreg[16];
#pragma unroll
      for (int k = 0; k < 16; ++k) mreg[k] = (float)mr[ln + 64*k];
      for (int a = 0; a < AA; ++a) {
        float p = 0.f;
#pragma unroll
        for (int k = 0; k < 16; ++k) p += mreg[k] * out_w[(size_t)a*HH + ln + 64*k];
        p = wred_sum(p);
        if (ln == 0) out[(size_t)row*AA + a] = p + out_b[a];
      }
    }
  }
  for (int i = bk*256 + tid; i < BB*HH; i += 256*256)
    out[QSZ + BB*HH + i] = cf[i];
}

// ---------------- host launch ----------------
extern "C" void kernel_launch(void* const* d_in, const int* in_sizes, int n_in,
                              void* d_out, int out_size, void* d_ws, size_t ws_size,
                              hipStream_t stream) {
  (void)in_sizes; (void)n_in; (void)out_size; (void)ws_size;
  const float* state    = (const float*)d_in[0];
  const float* demo     = (const float*)d_in[1];
  const int*   demlen   = (const int*)d_in[2];
  const float* h0       = (const float*)d_in[3];
  const float* c0       = (const float*)d_in[4];
  const float* enc_wih  = (const float*)d_in[5];
  const float* enc_whh  = (const float*)d_in[6];
  const float* enc_bih  = (const float*)d_in[7];
  const float* enc_bhh  = (const float*)d_in[8];
  const float* attn_w   = (const float*)d_in[9];
  const float* comb_w   = (const float*)d_in[11];
  const float* comb_b   = (const float*)d_in[12];
  const float* lstm_wih = (const float*)d_in[13];
  const float* lstm_whh = (const float*)d_in[14];
  const float* lstm_bih = (const float*)d_in[15];
  const float* lstm_bhh = (const float*)d_in[16];
  const float* mid_w    = (const float*)d_in[17];
  const float* mid_b    = (const float*)d_in[18];
  const float* out_w    = (const float*)d_in[19];
  const float* out_b    = (const float*)d_in[20];
  char* ws = (char*)d_ws;

  __bf16* wEnc  = (__bf16*)(ws + OFF_WENC);
  __bf16* wLstm = (__bf16*)(ws + OFF_WLSTM);
  __bf16* wComb = (__bf16*)(ws + OFF_WCOMB);
  __bf16* wMid  = (__bf16*)(ws + OFF_WMID);
  float*  bE    = (float*)(ws + OFF_BIASE);
  float*  bL    = (float*)(ws + OFF_BIASL);
  __bf16* demoC = (__bf16*)(ws + OFF_DEMO);
  __bf16* stateB= (__bf16*)(ws + OFF_STATE);
  __bf16* encB  = (__bf16*)(ws + OFF_ENC);
  __bf16* hdec  = (__bf16*)(ws + OFF_HDEC);
  __bf16* xall  = (__bf16*)(ws + OFF_XALL);
  __bf16* mf    = (__bf16*)(ws + OFF_MF);
  __bf16* attnS = (__bf16*)(ws + OFF_ATTNS);
  float*  cf    = (float*)(ws + OFF_CF);
  __bf16* hbE0  = (__bf16*)(ws + OFF_HBUF);
  __bf16* hbE1  = hbE0 + (size_t)BB*HH;
  __bf16* hbD0  = hbE1 + (size_t)BB*HH;
  __bf16* hbD1  = hbD0 + (size_t)BB*HH;
  float*  out   = (float*)d_out;

  k_prep<<<PGRID, 256, 0, stream>>>(enc_wih, enc_whh, enc_bih, enc_bhh,
                                    lstm_wih, lstm_whh, lstm_bih, lstm_bhh,
                                    comb_w, mid_w, demo, state, ws);
  for (int t = 0; t < LL; ++t) {
    __bf16* hR = (t & 1) ? hbE1 : hbE0;
    __bf16* hW = (t & 1) ? hbE0 : hbE1;
    k_enc_step<<<256, 1024, 0, stream>>>(demoC, wEnc, bE, hR, hW, encB, cf, t);
  }
  k_attn<<<256, 256, 0, stream>>>(demlen, h0, c0, attn_w, encB, attnS, hbD0, cf);
  k_x<<<256, 256, 0, stream>>>(attnS, stateB, wComb, comb_b, xall);
  for (int t = 0; t < TT; ++t) {
    __bf16* hR = (t & 1) ? hbD1 : hbD0;
    __bf16* hW = (t & 1) ? hbD0 : hbD1;
    k_dec_step<<<256, 1024, 0, stream>>>(xall, wLstm, bL, hR, hW, hdec, cf, out, t);
  }
  k_mid<<<256, 256, 0, stream>>>(hdec, wMid, mid_b, mf);
  k_out<<<256, 256, 0, stream>>>(mf, out_w, out_b, cf, out);
}